// Round 10
// baseline (85.801 us; speedup 1.0000x reference)
//
#include <hip/hip_runtime.h>

#define SEQ  2048
#define DH   64
#define QBLK 128         // q rows per q-block = 4 waves x 32
#define KBLK 64          // k/v rows per staged tile
#define NQB  (SEQ/QBLK)  // 16
#define NTIL (SEQ/KBLK)  // 32 tiles per bh
#define THR  11.5f       // defer-max threshold (log2 domain)
#define KPAT(r) ((((r)&3)) + 8*((r)>>2))   // 32x32 C/D row pattern
#define WS_NEEDED ((size_t)2 * 64 * SEQ * DH * 2)   // K+V bf16 images = 33.5 MB

typedef short bf16x8 __attribute__((ext_vector_type(8)));   // 8 bf16 bits = 4 VGPRs
typedef float f32x16 __attribute__((ext_vector_type(16)));

union V4U { unsigned int w[4]; bf16x8 v; };

// fp32 -> bf16 bits, round-to-nearest-even
__device__ __forceinline__ short bfbits(float f) {
    unsigned int u = __float_as_uint(f);
    u += 0x7fff + ((u >> 16) & 1);
    return (short)(u >> 16);
}
// packed 2xfp32 -> 2xbf16 in one VALU op
__device__ __forceinline__ unsigned int cvtpk(float lo, float hi) {
    unsigned int r;
    asm("v_cvt_pk_bf16_f32 %0, %1, %2" : "=v"(r) : "v"(lo), "v"(hi));
    return r;
}
// swizzled short-index into a [rows][64] bf16 tile (row stride 128 B)
__device__ __forceinline__ int swz(int row, int col) {
    return row * 64 + (col ^ ((row & 7) << 3));
}
// async global->LDS, 16B per lane; LDS dest = uniform base + lane*16
__device__ __forceinline__ void gload16(const void* g, void* l) {
    __builtin_amdgcn_global_load_lds(
        (const __attribute__((address_space(1))) unsigned int*)g,
        (__attribute__((address_space(3))) unsigned int*)l,
        16, 0, 0);
}

// ================= pre-pass: K/V -> bf16 swizzled tile images =================
__global__ __launch_bounds__(256) void prep_kv(const float* __restrict__ Kg,
                                               const float* __restrict__ Vg,
                                               short* __restrict__ Kimg,
                                               short* __restrict__ Vimg) {
    __shared__ __align__(16) short Vt[64 * 64];
    const int tid = threadIdx.x;
    const int t   = blockIdx.x & (NTIL - 1);
    const int bh  = blockIdx.x / NTIL;
    const int kb  = t * KBLK;

    const float* Kb = Kg + (size_t)bh * SEQ * DH;
    const float* Vb = Vg + (size_t)bh * SEQ * DH;
    short* kim = Kimg + ((size_t)bh * NTIL + t) * 4096;
    short* vim = Vimg + ((size_t)bh * NTIL + t) * 4096;

    {
        const int kr = tid >> 2, sd0 = (tid & 3) * 16;
        const float* src = Kb + (size_t)(kb + kr) * DH + sd0;
        const float4 a0 = *reinterpret_cast<const float4*>(src);
        const float4 a1 = *reinterpret_cast<const float4*>(src + 4);
        const float4 a2 = *reinterpret_cast<const float4*>(src + 8);
        const float4 a3 = *reinterpret_cast<const float4*>(src + 12);
        V4U u0, u1;
        u0.w[0] = cvtpk(a0.x, a0.y); u0.w[1] = cvtpk(a0.z, a0.w);
        u0.w[2] = cvtpk(a1.x, a1.y); u0.w[3] = cvtpk(a1.z, a1.w);
        u1.w[0] = cvtpk(a2.x, a2.y); u1.w[1] = cvtpk(a2.z, a2.w);
        u1.w[2] = cvtpk(a3.x, a3.y); u1.w[3] = cvtpk(a3.z, a3.w);
        *reinterpret_cast<bf16x8*>(&kim[swz(kr, sd0)])     = u0.v;
        *reinterpret_cast<bf16x8*>(&kim[swz(kr, sd0 + 8)]) = u1.v;
    }
    {
        const int vk = tid & 63, vd0 = (tid >> 6) * 16;
        const float* src = Vb + (size_t)(kb + vk) * DH + vd0;
        const float4 b0 = *reinterpret_cast<const float4*>(src);
        const float4 b1 = *reinterpret_cast<const float4*>(src + 4);
        const float4 b2 = *reinterpret_cast<const float4*>(src + 8);
        const float4 b3 = *reinterpret_cast<const float4*>(src + 12);
        const float vv[16] = {b0.x,b0.y,b0.z,b0.w, b1.x,b1.y,b1.z,b1.w,
                              b2.x,b2.y,b2.z,b2.w, b3.x,b3.y,b3.z,b3.w};
        #pragma unroll
        for (int i = 0; i < 16; ++i)
            Vt[swz(vd0 + i, vk)] = bfbits(vv[i]);
    }
    __syncthreads();
    *reinterpret_cast<bf16x8*>(&vim[tid * 16])     = *reinterpret_cast<const bf16x8*>(&Vt[tid * 16]);
    *reinterpret_cast<bf16x8*>(&vim[tid * 16 + 8]) = *reinterpret_cast<const bf16x8*>(&Vt[tid * 16 + 8]);
}

// ================= main kernel: paired q-blocks + depth-2 counted-vmcnt pipeline =================
#define STAGE(b_, t_) do {                                                   \
    const short* kim_ = kimg + (size_t)(t_) * 4096 + w * 1024 + lane * 8;    \
    const short* vim_ = vimg + (size_t)(t_) * 4096 + w * 1024 + lane * 8;    \
    gload16(kim_,       &Ks[b_][w * 1024]);                                  \
    gload16(kim_ + 512, &Ks[b_][w * 1024 + 512]);                            \
    gload16(vim_,       &Vt[b_][w * 1024]);                                  \
    gload16(vim_ + 512, &Vt[b_][w * 1024 + 512]);                            \
} while (0)

// per-q-block per-tile compute (wave-uniform early-out on causal limit)
__device__ __forceinline__ void tile_compute(
    const short* __restrict__ Ksb, const short* __restrict__ Vtb,
    int kb, int kend, int qw, int q, int h, int ql,
    const bf16x8 (&qb)[4], f32x16& o0, f32x16& o1, float& m, float& lsum)
{
    if (kb >= kend) return;
    const bool v2 = (kb + 32 < kend);

    // ---- S^T = K Q^T : lane owns q-col ql; rows k = kb + sb*32 + KPAT(r) + 4h ----
    f32x16 sT0, sT1;
    #pragma unroll
    for (int i = 0; i < 16; ++i) sT0[i] = 0.f;
    __builtin_amdgcn_s_setprio(1);
    #pragma unroll
    for (int dc = 0; dc < 4; ++dc) {
        const bf16x8 ka = *reinterpret_cast<const bf16x8*>(&Ksb[swz(ql, dc * 16 + h * 8)]);
        sT0 = __builtin_amdgcn_mfma_f32_32x32x16_bf16(ka, qb[dc], sT0, 0, 0, 0);
    }
    __builtin_amdgcn_s_setprio(0);
    if (v2) {
        #pragma unroll
        for (int i = 0; i < 16; ++i) sT1[i] = 0.f;
        __builtin_amdgcn_s_setprio(1);
        #pragma unroll
        for (int dc = 0; dc < 4; ++dc) {
            const bf16x8 ka = *reinterpret_cast<const bf16x8*>(&Ksb[swz(32 + ql, dc * 16 + h * 8)]);
            sT1 = __builtin_amdgcn_mfma_f32_32x32x16_bf16(ka, qb[dc], sT1, 0, 0, 0);
        }
        __builtin_amdgcn_s_setprio(0);
    }

    // ---- causal mask (boundary sub-blocks only) ----
    if (kb + 31 > qw) {
        #pragma unroll
        for (int r = 0; r < 16; ++r)
            if (kb + KPAT(r) + 4 * h > q) sT0[r] = -1e30f;
    }
    if (v2 && (kb + 63 > qw)) {
        #pragma unroll
        for (int r = 0; r < 16; ++r)
            if (kb + 32 + KPAT(r) + 4 * h > q) sT1[r] = -1e30f;
    }

    // ---- in-lane max + defer-max fast path ----
    float mx = sT0[0];
    #pragma unroll
    for (int r = 1; r < 16; ++r) mx = fmaxf(mx, sT0[r]);
    if (v2) {
        #pragma unroll
        for (int r = 0; r < 16; ++r) mx = fmaxf(mx, sT1[r]);
    }
    if (!__all(mx <= m + THR)) {     // slow path: full row max + O/l rescale
        mx = fmaxf(mx, __shfl_xor(mx, 32));
        const float mn  = fmaxf(m, mx);
        const float scl = __builtin_amdgcn_exp2f(m - mn);
        m = mn;
        lsum *= scl;
        #pragma unroll
        for (int r = 0; r < 16; ++r) {
            const float sr = __shfl(scl, KPAT(r) + 4 * h);
            o0[r] *= sr; o1[r] *= sr;
        }
    }

    // ---- P = exp2(S^T - m), lane-partial l, pack + half-exchange into A-frags ----
    bf16x8 pa[4];
    {
        float p0[16];
        #pragma unroll
        for (int r = 0; r < 16; ++r) p0[r] = __builtin_amdgcn_exp2f(sT0[r] - m);
        #pragma unroll
        for (int r = 0; r < 16; ++r) lsum += p0[r];
        #pragma unroll
        for (int oct = 0; oct < 2; ++oct) {
            const unsigned int A0 = cvtpk(p0[oct*8+0], p0[oct*8+1]);
            const unsigned int A1 = cvtpk(p0[oct*8+2], p0[oct*8+3]);
            const unsigned int B0 = cvtpk(p0[oct*8+4], p0[oct*8+5]);
            const unsigned int B1 = cvtpk(p0[oct*8+6], p0[oct*8+7]);
            const unsigned int s0 = h ? A0 : B0, s1 = h ? A1 : B1;
            const unsigned int r0 = (unsigned int)__shfl_xor((int)s0, 32);
            const unsigned int r1 = (unsigned int)__shfl_xor((int)s1, 32);
            V4U u;
            u.w[0] = h ? r0 : A0; u.w[1] = h ? r1 : A1;
            u.w[2] = h ? B0 : r0; u.w[3] = h ? B1 : r1;
            pa[oct] = u.v;
        }
    }
    if (v2) {
        float p1[16];
        #pragma unroll
        for (int r = 0; r < 16; ++r) p1[r] = __builtin_amdgcn_exp2f(sT1[r] - m);
        #pragma unroll
        for (int r = 0; r < 16; ++r) lsum += p1[r];
        #pragma unroll
        for (int oct = 0; oct < 2; ++oct) {
            const unsigned int A0 = cvtpk(p1[oct*8+0], p1[oct*8+1]);
            const unsigned int A1 = cvtpk(p1[oct*8+2], p1[oct*8+3]);
            const unsigned int B0 = cvtpk(p1[oct*8+4], p1[oct*8+5]);
            const unsigned int B1 = cvtpk(p1[oct*8+6], p1[oct*8+7]);
            const unsigned int s0 = h ? A0 : B0, s1 = h ? A1 : B1;
            const unsigned int r0 = (unsigned int)__shfl_xor((int)s0, 32);
            const unsigned int r1 = (unsigned int)__shfl_xor((int)s1, 32);
            V4U u;
            u.w[0] = h ? r0 : A0; u.w[1] = h ? r1 : A1;
            u.w[2] = h ? B0 : r0; u.w[3] = h ? B1 : r1;
            pa[2 + oct] = u.v;
        }
    }

    // ---- O += P V  (B-frags from transposed V tile) ----
    __builtin_amdgcn_s_setprio(1);
    #pragma unroll
    for (int kt = 0; kt < 2; ++kt) {
        const bf16x8 vb0 = *reinterpret_cast<const bf16x8*>(&Vtb[swz(ql,      kt * 16 + h * 8)]);
        const bf16x8 vb1 = *reinterpret_cast<const bf16x8*>(&Vtb[swz(32 + ql, kt * 16 + h * 8)]);
        o0 = __builtin_amdgcn_mfma_f32_32x32x16_bf16(pa[kt], vb0, o0, 0, 0, 0);
        o1 = __builtin_amdgcn_mfma_f32_32x32x16_bf16(pa[kt], vb1, o1, 0, 0, 0);
    }
    __builtin_amdgcn_s_setprio(0);
    if (v2) {
        __builtin_amdgcn_s_setprio(1);
        #pragma unroll
        for (int kt = 2; kt < 4; ++kt) {
            const bf16x8 vb0 = *reinterpret_cast<const bf16x8*>(&Vtb[swz(ql,      kt * 16 + h * 8)]);
            const bf16x8 vb1 = *reinterpret_cast<const bf16x8*>(&Vtb[swz(32 + ql, kt * 16 + h * 8)]);
            o0 = __builtin_amdgcn_mfma_f32_32x32x16_bf16(pa[kt], vb0, o0, 0, 0, 0);
            o1 = __builtin_amdgcn_mfma_f32_32x32x16_bf16(pa[kt], vb1, o1, 0, 0, 0);
        }
        __builtin_amdgcn_s_setprio(0);
    }
}

__device__ __forceinline__ void load_qfrags(const float* Qb, int q, int h, float SC,
                                            bf16x8 (&qb)[4]) {
    const float* qp = Qb + (size_t)q * DH + h * 8;
    #pragma unroll
    for (int dc = 0; dc < 4; ++dc) {
        const float4 a = *reinterpret_cast<const float4*>(qp + dc * 16);
        const float4 b = *reinterpret_cast<const float4*>(qp + dc * 16 + 4);
        V4U u;
        u.w[0] = cvtpk(a.x * SC, a.y * SC);
        u.w[1] = cvtpk(a.z * SC, a.w * SC);
        u.w[2] = cvtpk(b.x * SC, b.y * SC);
        u.w[3] = cvtpk(b.z * SC, b.w * SC);
        qb[dc] = u.v;
    }
}

__device__ __forceinline__ void epilogue_store(float* Ob, int qw, int h, int ql,
                                               const f32x16& o0, const f32x16& o1,
                                               float lsum) {
    lsum += __shfl_xor(lsum, 32);
    const float inv = 1.0f / lsum;
    #pragma unroll
    for (int r = 0; r < 16; ++r) {
        const float ir  = __shfl(inv, KPAT(r) + 4 * h);
        const size_t row = (size_t)(qw + KPAT(r) + 4 * h);
        Ob[row * DH + ql]      = o0[r] * ir;
        Ob[row * DH + 32 + ql] = o1[r] * ir;
    }
}

__global__ __launch_bounds__(256, 2) void attn_fwd(const float* __restrict__ Qg,
                                                   const short* __restrict__ Kimg,
                                                   const short* __restrict__ Vimg,
                                                   float* __restrict__ Og) {
    __shared__ __align__(16) short Ks[3][64 * 64];   // K tiles, swizzled, tri-buffer
    __shared__ __align__(16) short Vt[3][64 * 64];   // V tiles, swizzled, tri-buffer

    const int tid  = threadIdx.x;
    const int w    = tid >> 6;
    const int lane = tid & 63;
    const int h    = lane >> 5;      // half-wave (k-chunk selector)
    const int ql   = lane & 31;      // lane's q-col (S^T) / d-col (O)

    // paired q-blocks: A = p, B = 15-p -> per-wave work uniform by construction.
    const int p   = blockIdx.x & 7;
    const int bh  = blockIdx.x >> 3;
    const int qblkA = p, qblkB = NQB - 1 - p;

    const float* Qb   = Qg + (size_t)bh * SEQ * DH;
    const short* kimg = Kimg + (size_t)bh * NTIL * 4096;
    const short* vimg = Vimg + (size_t)bh * NTIL * 4096;
    float*       Ob   = Og + (size_t)bh * SEQ * DH;

    const float SC = 0.125f * 1.44269504f;   // 1/sqrt(64) * log2(e)

    const int qwA = qblkA * QBLK + w * 32, qA = qwA + ql, kendA = qwA + 32;
    const int qwB = qblkB * QBLK + w * 32, qB = qwB + ql, kendB = qwB + 32;
    const int nt  = qblkB * 2 + 2;          // >= 18

    // prologue: stage tiles 0 and 1, then full drain (clean pipeline state)
    STAGE(0, 0);
    STAGE(1, 1);

    bf16x8 qbA[4], qbB[4];
    load_qfrags(Qb, qA, h, SC, qbA);
    load_qfrags(Qb, qB, h, SC, qbB);

    f32x16 oA0, oA1, oB0, oB1;
    #pragma unroll
    for (int i = 0; i < 16; ++i) { oA0[i]=0.f; oA1[i]=0.f; oB0[i]=0.f; oB1[i]=0.f; }
    float mA = -1e30f, lA = 0.f, mB = -1e30f, lB = 0.f;

    __syncthreads();                  // drains vmcnt(0): tiles 0,1 resident

    for (int t = 0; t < nt; ++t) {
        const int kb  = t * KBLK;
        const int cur = t % 3;

        // counted-vmcnt pipeline: drain tile t's 4 loads only; keep later
        // tiles' loads in flight ACROSS the barrier (T3/T4). Wave issues
        // exactly 4 gloads/tile, so vmcnt(4) == "all but the newest tile".
        if (t + 1 < nt) asm volatile("s_waitcnt vmcnt(4)" ::: "memory");
        else            asm volatile("s_waitcnt vmcnt(0)" ::: "memory");
        __builtin_amdgcn_s_barrier();
        __builtin_amdgcn_sched_barrier(0);   // no motion across the barrier

        if (t + 2 < nt) STAGE((t + 2) % 3, t + 2);   // issue early (T14)

        tile_compute(&Ks[cur][0], &Vt[cur][0], kb, kendA, qwA, qA, h, ql,
                     qbA, oA0, oA1, mA, lA);
        tile_compute(&Ks[cur][0], &Vt[cur][0], kb, kendB, qwB, qB, h, ql,
                     qbB, oB0, oB1, mB, lB);
    }

    epilogue_store(Ob, qwA, h, ql, oA0, oA1, lA);
    epilogue_store(Ob, qwB, h, ql, oB0, oB1, lB);
}

// ================= fallback (reg-staged, used if ws too small) =================
#define LOAD_STAGE(kb_) do {                                               \
    const float* ksrc = Kb + (size_t)((kb_) + skr) * DH + sd0;             \
    kr0 = *reinterpret_cast<const float4*>(ksrc);                          \
    kr1 = *reinterpret_cast<const float4*>(ksrc + 4);                      \
    kr2 = *reinterpret_cast<const float4*>(ksrc + 8);                      \
    kr3 = *reinterpret_cast<const float4*>(ksrc + 12);                     \
    const float* vsrc = Vb + (size_t)((kb_) + svk) * DH + svd0;            \
    vr0 = *reinterpret_cast<const float4*>(vsrc);                          \
    vr1 = *reinterpret_cast<const float4*>(vsrc + 4);                      \
    vr2 = *reinterpret_cast<const float4*>(vsrc + 8);                      \
    vr3 = *reinterpret_cast<const float4*>(vsrc + 12);                     \
} while (0)

#define CVT_WRITE(b_) do {                                                 \
    V4U u0, u1;                                                            \
    u0.w[0] = cvtpk(kr0.x, kr0.y); u0.w[1] = cvtpk(kr0.z, kr0.w);          \
    u0.w[2] = cvtpk(kr1.x, kr1.y); u0.w[3] = cvtpk(kr1.z, kr1.w);          \
    u1.w[0] = cvtpk(kr2.x, kr2.y); u1.w[1] = cvtpk(kr2.z, kr2.w);          \
    u1.w[2] = cvtpk(kr3.x, kr3.y); u1.w[3] = cvtpk(kr3.z, kr3.w);          \
    *reinterpret_cast<bf16x8*>(&Ks[b_][swz(skr, sd0)])     = u0.v;         \
    *reinterpret_cast<bf16x8*>(&Ks[b_][swz(skr, sd0 + 8)]) = u1.v;         \
    const float vv[16] = {vr0.x,vr0.y,vr0.z,vr0.w, vr1.x,vr1.y,vr1.z,vr1.w,\
                          vr2.x,vr2.y,vr2.z,vr2.w, vr3.x,vr3.y,vr3.z,vr3.w};\
    _Pragma("unroll")                                                      \
    for (int i_ = 0; i_ < 16; ++i_)                                        \
        Vt[b_][swz(svd0 + i_, svk)] = bfbits(vv[i_]);                      \
} while (0)

__global__ __launch_bounds__(256) void attn_fwd_fb(const float* __restrict__ Qg,
                                                   const float* __restrict__ Kg,
                                                   const float* __restrict__ Vg,
                                                   float* __restrict__ Og) {
    __shared__ __align__(16) short Ks[2][64 * 64];
    __shared__ __align__(16) short Vt[2][64 * 64];

    const int tid  = threadIdx.x;
    const int w    = tid >> 6;
    const int lane = tid & 63;
    const int h    = lane >> 5;
    const int ql   = lane & 31;

    const int j    = blockIdx.x & (NQB - 1);
    const int bh   = blockIdx.x / NQB;
    const int qblk = ((bh >> 4) & 1) ? (NQB - 1 - j) : j;
    const int q0   = qblk * QBLK;
    const int qw   = q0 + w * 32;
    const int q    = qw + ql;

    const float* Qb = Qg + (size_t)bh * SEQ * DH;
    const float* Kb = Kg + (size_t)bh * SEQ * DH;
    const float* Vb = Vg + (size_t)bh * SEQ * DH;
    float*       Ob = Og + (size_t)bh * SEQ * DH;

    const float SC = 0.125f * 1.44269504f;

    const int skr  = tid >> 2;
    const int sd0  = (tid & 3) * 16;
    const int svk  = tid & 63;
    const int svd0 = (tid >> 6) * 16;

    float4 kr0, kr1, kr2, kr3, vr0, vr1, vr2, vr3;
    LOAD_STAGE(0);

    bf16x8 qb[4];
    load_qfrags(Qb, q, h, SC, qb);

    f32x16 o0, o1;
    #pragma unroll
    for (int i = 0; i < 16; ++i) { o0[i] = 0.f; o1[i] = 0.f; }
    float m = -1e30f, lsum = 0.f;

    CVT_WRITE(0);
    __syncthreads();

    const int kend = qw + 32;
    const int nt   = (q0 + QBLK) / KBLK;

    for (int t = 0; t < nt; ++t) {
        const int kb  = t * KBLK;
        const int cur = t & 1;
        if (t + 1 < nt) LOAD_STAGE(kb + KBLK);

        tile_compute(&Ks[cur][0], &Vt[cur][0], kb, kend, qw, q, h, ql,
                     qb, o0, o1, m, lsum);

        if (t + 1 < nt) CVT_WRITE(cur ^ 1);
        __syncthreads();
    }

    epilogue_store(Ob, qw, h, ql, o0, o1, lsum);
}

extern "C" void kernel_launch(void* const* d_in, const int* in_sizes, int n_in,
                              void* d_out, int out_size, void* d_ws, size_t ws_size,
                              hipStream_t stream) {
    const float* Q = (const float*)d_in[0];
    const float* K = (const float*)d_in[1];
    const float* V = (const float*)d_in[2];
    // d_in[3] causal mask: synthesized in-kernel, not read.
    float* O = (float*)d_out;

    if (ws_size >= WS_NEEDED) {
        short* Kimg = (short*)d_ws;
        short* Vimg = Kimg + (size_t)64 * NTIL * 4096;
        prep_kv<<<dim3(64 * NTIL), 256, 0, stream>>>(K, V, Kimg, Vimg);
        attn_fwd<<<dim3(64 * (NQB / 2)), 256, 0, stream>>>(Q, Kimg, Vimg, O);
    } else {
        attn_fwd_fb<<<dim3(64 * NQB), 256, 0, stream>>>(Q, K, V, O);
    }
}